// Round 6
// baseline (814.374 us; speedup 1.0000x reference)
//
#include <hip/hip_runtime.h>

#define N_NODES 250000
#define N_EDGES 4000000
#define N_GRAPHS 512
#define NEG 0.01f
#define BINB 9
#define WIN 512
#define NBINS 489            // ceil(250000 / 512)
#define CAP 9216             // bin capacity: mean 8192 + ~11 sigma (90)
#define PART_EPB 4096
#define PART_BLOCKS 977      // 977 * 4096 >= N_EDGES
#define INVW 0xFFFFFFFFu

__device__ __forceinline__ float lrelu(float v) { return v > 0.0f ? v : NEG * v; }

// ---- Pad x (13 floats/row) into x16 (16 floats/row, one cache line) ----
__global__ void pad_x(const float* __restrict__ x, float* __restrict__ x16) {
    int tid = blockIdx.x * blockDim.x + threadIdx.x;
    if (tid >= N_NODES * 16) return;
    int n = tid >> 4, j = tid & 15;
    x16[tid] = (j < 13) ? x[n * 13 + j] : 0.0f;
}

// ---- Edge binning: one pass, per-block chunk reservation ---------------
__global__ void partition_k(const int* __restrict__ src, const int* __restrict__ dst,
                            int* __restrict__ bin_cnt, unsigned* __restrict__ binned) {
    __shared__ int hist[NBINS];
    __shared__ int base[NBINS];
    __shared__ int cur[NBINS];
    int t = threadIdx.x;
    for (int i = t; i < NBINS; i += 256) { hist[i] = 0; cur[i] = 0; }
    __syncthreads();
    unsigned e0 = blockIdx.x * PART_EPB;
    int sw[16], dw[16];
#pragma unroll
    for (int i = 0; i < 16; i++) {
        unsigned e = e0 + (unsigned)i * 256u + t;
        if (e < N_EDGES) {
            sw[i] = src[e];
            dw[i] = dst[e];
            atomicAdd(&hist[dw[i] >> BINB], 1);
        } else {
            dw[i] = -1;
        }
    }
    __syncthreads();
    for (int i = t; i < NBINS; i += 256)
        if (hist[i] > 0) base[i] = atomicAdd(&bin_cnt[i], hist[i]);
    __syncthreads();
#pragma unroll
    for (int i = 0; i < 16; i++) {
        if (dw[i] >= 0) {
            int b = dw[i] >> BINB;
            int pos = atomicAdd(&cur[b], 1);
            binned[(unsigned)b * CAP + (unsigned)(base[b] + pos)] =
                ((unsigned)(dw[i] & (WIN - 1)) << 18) | (unsigned)sw[i];
        }
    }
}

// ---- Layer-1 aggregation: 4 lanes/edge float4 on x16, P=4 pipelined ----
__global__ __launch_bounds__(1024) void agg13_k(const float* __restrict__ x16,
                                                const unsigned* __restrict__ binned,
                                                const int* __restrict__ bin_cnt,
                                                float* __restrict__ agg,
                                                float* __restrict__ cntf) {
    __shared__ float acc[WIN * 14];  // 28 KB
    int t = threadIdx.x;
    for (int i = t; i < WIN * 14; i += 1024) acc[i] = 0.0f;
    __syncthreads();
    int bin = blockIdx.x;
    int cnt = bin_cnt[bin];
    const unsigned* bp = binned + (size_t)bin * CAP;
    int g = t >> 2, j4 = t & 3;
    const int S = 256;
    constexpr int P = 4;
    for (int k0 = g; k0 < cnt; k0 += P * S) {
        unsigned w[P];
        float4 v[P];
#pragma unroll
        for (int p = 0; p < P; p++) {
            int k = k0 + p * S;
            w[p] = (k < cnt) ? bp[k] : INVW;
        }
#pragma unroll
        for (int p = 0; p < P; p++) {
            unsigned s = min(w[p] & 0x3FFFFu, (unsigned)(N_NODES - 1));
            v[p] = *(const float4*)&x16[(size_t)s * 16u + (unsigned)(j4 * 4)];
        }
#pragma unroll
        for (int p = 0; p < P; p++) {
            if (w[p] != INVW) {
                unsigned f = w[p] >> 18;
                float* a = &acc[f * 14u + (unsigned)(j4 * 4)];
                if (j4 < 3) {
                    atomicAdd(a + 0, v[p].x); atomicAdd(a + 1, v[p].y);
                    atomicAdd(a + 2, v[p].z); atomicAdd(a + 3, v[p].w);
                } else {
                    atomicAdd(a + 0, v[p].x);   // dim 12
                    atomicAdd(a + 1, 1.0f);     // degree in col 13
                }
            }
        }
    }
    __syncthreads();
    int n0 = bin << BINB;
    int nodes = min(WIN, N_NODES - n0);
    for (int idx = t; idx < nodes * 13; idx += 1024) {
        int r = idx / 13, c = idx - r * 13;
        agg[(size_t)n0 * 13u + idx] = acc[r * 14 + c];
    }
    for (int r = t; r < nodes; r += 1024) cntf[n0 + r] = acc[r * 14 + 13];
}

// ---- Layer-2/3 aggregation: D/4 lanes/edge float4, P=4 pipelined -------
template <int D>
__global__ __launch_bounds__(1024) void aggD_k(const float* __restrict__ feat,
                                               const unsigned* __restrict__ binned,
                                               const int* __restrict__ bin_cnt,
                                               float* __restrict__ agg) {
    constexpr int LPE = D / 4;
    constexpr int SLOTS = 1024 / LPE;
    constexpr int P = 4;
    __shared__ float acc[WIN * D];
    int t = threadIdx.x;
    for (int i = t; i < WIN * D; i += 1024) acc[i] = 0.0f;
    __syncthreads();
    int bin = blockIdx.x;
    int cnt = bin_cnt[bin];
    const unsigned* bp = binned + (size_t)bin * CAP;
    int g = t / LPE, l = t % LPE;
    for (int k0 = g; k0 < cnt; k0 += P * SLOTS) {
        unsigned w[P];
        float4 v[P];
#pragma unroll
        for (int p = 0; p < P; p++) {
            int k = k0 + p * SLOTS;
            w[p] = (k < cnt) ? bp[k] : INVW;
        }
#pragma unroll
        for (int p = 0; p < P; p++) {
            unsigned s = min(w[p] & 0x3FFFFu, (unsigned)(N_NODES - 1));
            v[p] = *(const float4*)&feat[(size_t)s * D + l * 4];
        }
#pragma unroll
        for (int p = 0; p < P; p++) {
            if (w[p] != INVW) {
                unsigned f = w[p] >> 18;
                float* a = &acc[f * D + l * 4];
                atomicAdd(a + 0, v[p].x); atomicAdd(a + 1, v[p].y);
                atomicAdd(a + 2, v[p].z); atomicAdd(a + 3, v[p].w);
            }
        }
    }
    __syncthreads();
    int n0 = bin << BINB;
    int nodes = min(WIN, N_NODES - n0);
    for (int idx = t; idx < nodes * D; idx += 1024)
        agg[(size_t)n0 * D + idx] = acc[idx];
}

// ---- Node-side fused linears -------------------------------------------

// h1 = lrelu(agg13/cnt @W1l + b1 + x@W1r); y2 = h1@W2l; z2 = h1@W2r
__global__ void fused1(const float* __restrict__ agg, const float* __restrict__ x,
                       const float* __restrict__ cntf,
                       const float* __restrict__ W1l, const float* __restrict__ b1,
                       const float* __restrict__ W1r, const float* __restrict__ W2l,
                       const float* __restrict__ W2r,
                       float* __restrict__ y2, float* __restrict__ z2) {
    __shared__ float sWl[208], sWr[208], sb[16], sA[128], sB[128];
    for (int i = threadIdx.x; i < 208; i += blockDim.x) { sWl[i] = W1l[i]; sWr[i] = W1r[i]; }
    for (int i = threadIdx.x; i < 128; i += blockDim.x) { sA[i] = W2l[i]; sB[i] = W2r[i]; }
    if (threadIdx.x < 16) sb[threadIdx.x] = b1[threadIdx.x];
    __syncthreads();
    int n = blockIdx.x * blockDim.x + threadIdx.x;
    if (n >= N_NODES) return;
    float inv = 1.0f / fmaxf(cntf[n], 1.0f);
    float a[13], xv[13];
#pragma unroll
    for (int i = 0; i < 13; i++) { a[i] = agg[n * 13 + i] * inv; xv[i] = x[n * 13 + i]; }
    float h[16];
#pragma unroll
    for (int o = 0; o < 16; o++) {
        float acc = sb[o];
#pragma unroll
        for (int i = 0; i < 13; i++) acc += a[i] * sWl[i * 16 + o] + xv[i] * sWr[i * 16 + o];
        h[o] = lrelu(acc);
    }
#pragma unroll
    for (int o2 = 0; o2 < 8; o2++) {
        float ya = 0.0f, za = 0.0f;
#pragma unroll
        for (int o = 0; o < 16; o++) { ya += h[o] * sA[o * 8 + o2]; za += h[o] * sB[o * 8 + o2]; }
        y2[n * 8 + o2] = ya;
        z2[n * 8 + o2] = za;
    }
}

// h2 = lrelu(agg8/cnt + b2 + z2) (in place over z2); y3 = h2@W3l
__global__ void fused2(const float* __restrict__ agg8, const float* __restrict__ cntf,
                       const float* __restrict__ b2, const float* __restrict__ W3l,
                       float* __restrict__ z2h2, float* __restrict__ y3) {
    __shared__ float sb[8], sW3[32];
    if (threadIdx.x < 8) sb[threadIdx.x] = b2[threadIdx.x];
    if (threadIdx.x < 32) sW3[threadIdx.x] = W3l[threadIdx.x];
    __syncthreads();
    int n = blockIdx.x * blockDim.x + threadIdx.x;
    if (n >= N_NODES) return;
    float inv = 1.0f / fmaxf(cntf[n], 1.0f);
    float h2v[8];
#pragma unroll
    for (int j = 0; j < 8; j++) {
        float v = agg8[n * 8 + j] * inv + sb[j] + z2h2[n * 8 + j];
        h2v[j] = lrelu(v);
        z2h2[n * 8 + j] = h2v[j];
    }
#pragma unroll
    for (int k = 0; k < 4; k++) {
        float acc = 0.0f;
#pragma unroll
        for (int j = 0; j < 8; j++) acc += h2v[j] * sW3[j * 4 + k];
        y3[n * 4 + k] = acc;
    }
}

// h3 = agg4/cnt + b3 + h2@W3r; pooled (sorted batch -> LDS window).
__global__ void pool_k(const float* __restrict__ agg4, const float* __restrict__ h2,
                       const float* __restrict__ cntf,
                       const float* __restrict__ W3r, const float* __restrict__ b3,
                       const int* __restrict__ batch,
                       float* __restrict__ pool, float* __restrict__ gcnt) {
    __shared__ float sW[32], sb[4];
    __shared__ float lp[16][4];
    __shared__ float lc[16];
    __shared__ int sbase;
    if (threadIdx.x < 32) sW[threadIdx.x] = W3r[threadIdx.x];
    if (threadIdx.x < 4) sb[threadIdx.x] = b3[threadIdx.x];
    if (threadIdx.x < 16) {
        lc[threadIdx.x] = 0.0f;
        for (int k = 0; k < 4; k++) lp[threadIdx.x][k] = 0.0f;
    }
    int n0 = blockIdx.x * blockDim.x;
    if (threadIdx.x == 0) sbase = batch[n0 < N_NODES ? n0 : N_NODES - 1];
    __syncthreads();
    int n = n0 + threadIdx.x;
    if (n < N_NODES) {
        int b = batch[n];
        float inv = 1.0f / fmaxf(cntf[n], 1.0f);
        float h2v[8];
#pragma unroll
        for (int j = 0; j < 8; j++) h2v[j] = h2[n * 8 + j];
        int off = b - sbase;
        bool local = (off >= 0 && off < 16);
#pragma unroll
        for (int k = 0; k < 4; k++) {
            float z = 0.0f;
#pragma unroll
            for (int j = 0; j < 8; j++) z += h2v[j] * sW[j * 4 + k];
            float v = agg4[n * 4 + k] * inv + sb[k] + z;
            if (local) atomicAdd(&lp[off][k], v);
            else atomicAdd(&pool[b * 4 + k], v);
        }
        if (local) atomicAdd(&lc[off], 1.0f);
        else atomicAdd(&gcnt[b], 1.0f);
    }
    __syncthreads();
    if (threadIdx.x < 16) {
        int b = sbase + threadIdx.x;
        float c = lc[threadIdx.x];
        if (c > 0.0f && b < N_GRAPHS) {
            atomicAdd(&gcnt[b], c);
            for (int k = 0; k < 4; k++) atomicAdd(&pool[b * 4 + k], lp[threadIdx.x][k]);
        }
    }
}

__global__ void final_k(const float* __restrict__ pool, const float* __restrict__ gcnt,
                        const float* __restrict__ Wc, const float* __restrict__ bc,
                        float* __restrict__ out) {
    int g = blockIdx.x * blockDim.x + threadIdx.x;
    if (g >= N_GRAPHS) return;
    float inv = 1.0f / fmaxf(gcnt[g], 1.0f);
    float acc = bc[0];
#pragma unroll
    for (int k = 0; k < 4; k++) {
        float ap = pool[g * 4 + k];
        acc += ap * inv * Wc[k] + ap * Wc[4 + k];
    }
    out[g] = acc;
}

extern "C" void kernel_launch(void* const* d_in, const int* in_sizes, int n_in,
                              void* d_out, int out_size, void* d_ws, size_t ws_size,
                              hipStream_t stream) {
    const float* x = (const float*)d_in[0];
    const int* ei = (const int*)d_in[1];
    const int* src = ei;
    const int* dst = ei + N_EDGES;
    const int* batch = (const int*)d_in[2];
    const float* W1l = (const float*)d_in[3];
    const float* b1 = (const float*)d_in[4];
    const float* W1r = (const float*)d_in[5];
    const float* W2l = (const float*)d_in[6];
    const float* b2 = (const float*)d_in[7];
    const float* W2r = (const float*)d_in[8];
    const float* W3l = (const float*)d_in[9];
    const float* b3 = (const float*)d_in[10];
    const float* W3r = (const float*)d_in[11];
    const float* Wc = (const float*)d_in[12];
    const float* bc = (const float*)d_in[13];
    float* out = (float*)d_out;

    const size_t N = N_NODES;
    // layout: binned (NBINS*CAP u32 ~= 18.0 MB) | bin_cnt (512) | floats
    unsigned* binned = (unsigned*)d_ws;
    int* bin_cnt = (int*)(binned + (size_t)NBINS * CAP);
    float* fbase = (float*)(bin_cnt + 512);
    float* agg = fbase;                 // 13N (reused: agg8 [0,8N), agg4 [0,4N))
    float* y3 = agg + 8 * N;            // 4N overlay in agg's upper region
    float* cntf = fbase + 13 * N;       // N
    float* y2 = cntf + N;               // 8N
    float* z2 = y2 + 8 * N;             // 8N (becomes h2 in place)
    float* x16 = y2;                    // 16N alias over y2+z2 (dead after agg13)
    float* pool = z2 + 8 * N;           // 2048
    float* gcnt = pool + N_GRAPHS * 4;  // 512

    const int TPB = 256;
    const int NB = (N_NODES + TPB - 1) / TPB;

    hipMemsetAsync(bin_cnt, 0, 512 * sizeof(int), stream);
    hipMemsetAsync(pool, 0, N_GRAPHS * 5 * sizeof(float), stream);

    // Prep: pad x to 64-B rows; bin edges by dst>>9 (reused by all layers).
    pad_x<<<(N_NODES * 16) / TPB, TPB, 0, stream>>>(x, x16);
    partition_k<<<PART_BLOCKS, TPB, 0, stream>>>(src, dst, bin_cnt, binned);

    // Layer 1: LDS-aggregate x16 (13 dims + degree), fused node linear.
    agg13_k<<<NBINS, 1024, 0, stream>>>(x16, binned, bin_cnt, agg, cntf);
    fused1<<<NB, TPB, 0, stream>>>(agg, x, cntf, W1l, b1, W1r, W2l, W2r, y2, z2);

    // Layer 2: LDS-aggregate y2 (8 dims), epilogue -> h2 (in z2), y3.
    aggD_k<8><<<NBINS, 1024, 0, stream>>>(y2, binned, bin_cnt, agg);
    fused2<<<NB, TPB, 0, stream>>>(agg, cntf, b2, W3l, z2, y3);

    // Layer 3: LDS-aggregate y3 (4 dims), epilogue + pooling.
    aggD_k<4><<<NBINS, 1024, 0, stream>>>(y3, binned, bin_cnt, agg);
    pool_k<<<NB, TPB, 0, stream>>>(agg, z2, cntf, W3r, b3, batch, pool, gcnt);

    final_k<<<2, TPB, 0, stream>>>(pool, gcnt, Wc, bc, out);
}

// Round 7
// 805.241 us; speedup vs baseline: 1.0113x; 1.0113x over previous
//
#include <hip/hip_runtime.h>

#define N_NODES 250000
#define N_EDGES 4000000
#define N_GRAPHS 512
#define NEG 0.01f
#define BINB 9
#define WIN 512
#define NBINS 489            // ceil(250000 / 512)
#define CAP 9216             // bin capacity: mean 8192 + ~11 sigma (90)
#define PART_EPB 4096
#define PART_BLOCKS 977      // 977 * 4096 >= N_EDGES
#define INVW 0xFFFFFFFFu

__device__ __forceinline__ float lrelu(float v) { return v > 0.0f ? v : NEG * v; }
// bf16 pack (RNE) / unpack helpers, bit-level (no type headaches)
__device__ __forceinline__ unsigned f2b(float f) {
    unsigned u = __float_as_uint(f);
    unsigned r = ((u >> 16) & 1u) + 0x7FFFu;
    return (u + r) >> 16;
}
__device__ __forceinline__ unsigned pk(float a, float b) { return f2b(a) | (f2b(b) << 16); }
__device__ __forceinline__ float blo(unsigned p) { return __uint_as_float(p << 16); }
__device__ __forceinline__ float bhi(unsigned p) { return __uint_as_float(p & 0xFFFF0000u); }

// ---- Pack x (13 f32) into x16b (16 bf16 = 32 B rows) -------------------
__global__ void pack_x(const float* __restrict__ x, unsigned* __restrict__ x16b) {
    int tid = blockIdx.x * blockDim.x + threadIdx.x;
    if (tid >= N_NODES * 8) return;
    int n = tid >> 3, d2 = tid & 7;
    int a = d2 * 2, b = a + 1;
    float va = (a < 13) ? x[n * 13 + a] : 0.0f;
    float vb = (b < 13) ? x[n * 13 + b] : 0.0f;
    x16b[tid] = pk(va, vb);
}

// ---- Edge binning: one pass, per-block chunk reservation ---------------
__global__ void partition_k(const int* __restrict__ src, const int* __restrict__ dst,
                            int* __restrict__ bin_cnt, unsigned* __restrict__ binned) {
    __shared__ int hist[NBINS];
    __shared__ int base[NBINS];
    __shared__ int cur[NBINS];
    int t = threadIdx.x;
    for (int i = t; i < NBINS; i += 256) { hist[i] = 0; cur[i] = 0; }
    __syncthreads();
    unsigned e0 = blockIdx.x * PART_EPB;
    int sw[16], dw[16];
#pragma unroll
    for (int i = 0; i < 16; i++) {
        unsigned e = e0 + (unsigned)i * 256u + t;
        if (e < N_EDGES) {
            sw[i] = src[e];
            dw[i] = dst[e];
            atomicAdd(&hist[dw[i] >> BINB], 1);
        } else {
            dw[i] = -1;
        }
    }
    __syncthreads();
    for (int i = t; i < NBINS; i += 256)
        if (hist[i] > 0) base[i] = atomicAdd(&bin_cnt[i], hist[i]);
    __syncthreads();
#pragma unroll
    for (int i = 0; i < 16; i++) {
        if (dw[i] >= 0) {
            int b = dw[i] >> BINB;
            int pos = atomicAdd(&cur[b], 1);
            binned[(unsigned)b * CAP + (unsigned)(base[b] + pos)] =
                ((unsigned)(dw[i] & (WIN - 1)) << 18) | (unsigned)sw[i];
        }
    }
}

// ---- Layer-1 aggregation: 2 lanes/edge, 16 B bf16 loads, P=4 ----------
__global__ __launch_bounds__(1024) void agg13_k(const unsigned* __restrict__ x16b,
                                                const unsigned* __restrict__ binned,
                                                const int* __restrict__ bin_cnt,
                                                float* __restrict__ agg,
                                                float* __restrict__ cntf) {
    __shared__ float acc[WIN * 14];  // 28 KB
    int t = threadIdx.x;
    for (int i = t; i < WIN * 14; i += 1024) acc[i] = 0.0f;
    __syncthreads();
    int bin = blockIdx.x;
    int cnt = bin_cnt[bin];
    const unsigned* bp = binned + (size_t)bin * CAP;
    int g = t >> 1, l = t & 1;   // 512 edge-slots, lane l covers dims l*8..l*8+7
    const int S = 512;
    constexpr int P = 4;
    for (int k0 = g; k0 < cnt; k0 += P * S) {
        unsigned w[P];
        uint4 q[P];
#pragma unroll
        for (int p = 0; p < P; p++) {
            int k = k0 + p * S;
            w[p] = (k < cnt) ? bp[k] : INVW;
        }
#pragma unroll
        for (int p = 0; p < P; p++) {
            unsigned s = min(w[p] & 0x3FFFFu, (unsigned)(N_NODES - 1));
            q[p] = *(const uint4*)&x16b[(size_t)s * 8u + (unsigned)(l * 4)];
        }
#pragma unroll
        for (int p = 0; p < P; p++) {
            if (w[p] != INVW) {
                unsigned f = w[p] >> 18;
                float* a = &acc[f * 14u + (unsigned)(l * 8)];
                atomicAdd(a + 0, blo(q[p].x)); atomicAdd(a + 1, bhi(q[p].x));
                atomicAdd(a + 2, blo(q[p].y)); atomicAdd(a + 3, bhi(q[p].y));
                atomicAdd(a + 4, blo(q[p].z));
                if (l == 0) {
                    atomicAdd(a + 5, bhi(q[p].z));
                    atomicAdd(a + 6, blo(q[p].w)); atomicAdd(a + 7, bhi(q[p].w));
                } else {
                    atomicAdd(a + 5, 1.0f);  // degree in col 13 (dims 13..15 are zero pad)
                }
            }
        }
    }
    __syncthreads();
    int n0 = bin << BINB;
    int nodes = min(WIN, N_NODES - n0);
    for (int idx = t; idx < nodes * 13; idx += 1024) {
        int r = idx / 13, c = idx - r * 13;
        agg[(size_t)n0 * 13u + idx] = acc[r * 14 + c];
    }
    for (int r = t; r < nodes; r += 1024) cntf[n0 + r] = acc[r * 14 + 13];
}

// ---- Layer-2 aggregation: 1 lane/edge, 16 B bf16 (8 dims), P=4 --------
__global__ __launch_bounds__(1024) void agg8_k(const unsigned* __restrict__ y2b,
                                               const unsigned* __restrict__ binned,
                                               const int* __restrict__ bin_cnt,
                                               float* __restrict__ agg) {
    __shared__ float acc[WIN * 8];
    int t = threadIdx.x;
    for (int i = t; i < WIN * 8; i += 1024) acc[i] = 0.0f;
    __syncthreads();
    int bin = blockIdx.x;
    int cnt = bin_cnt[bin];
    const unsigned* bp = binned + (size_t)bin * CAP;
    constexpr int P = 4;
    for (int k0 = t; k0 < cnt; k0 += P * 1024) {
        unsigned w[P];
        uint4 q[P];
#pragma unroll
        for (int p = 0; p < P; p++) {
            int k = k0 + p * 1024;
            w[p] = (k < cnt) ? bp[k] : INVW;
        }
#pragma unroll
        for (int p = 0; p < P; p++) {
            unsigned s = min(w[p] & 0x3FFFFu, (unsigned)(N_NODES - 1));
            q[p] = *(const uint4*)&y2b[(size_t)s * 4u];
        }
#pragma unroll
        for (int p = 0; p < P; p++) {
            if (w[p] != INVW) {
                unsigned f = w[p] >> 18;
                float* a = &acc[f * 8u];
                atomicAdd(a + 0, blo(q[p].x)); atomicAdd(a + 1, bhi(q[p].x));
                atomicAdd(a + 2, blo(q[p].y)); atomicAdd(a + 3, bhi(q[p].y));
                atomicAdd(a + 4, blo(q[p].z)); atomicAdd(a + 5, bhi(q[p].z));
                atomicAdd(a + 6, blo(q[p].w)); atomicAdd(a + 7, bhi(q[p].w));
            }
        }
    }
    __syncthreads();
    int n0 = bin << BINB;
    int nodes = min(WIN, N_NODES - n0);
    for (int idx = t; idx < nodes * 8; idx += 1024)
        agg[(size_t)n0 * 8u + idx] = acc[idx];
}

// ---- Layer-3 aggregation: 1 lane/edge, 8 B bf16 (4 dims), P=4 ---------
__global__ __launch_bounds__(1024) void agg4_k(const unsigned* __restrict__ y3b,
                                               const unsigned* __restrict__ binned,
                                               const int* __restrict__ bin_cnt,
                                               float* __restrict__ agg) {
    __shared__ float acc[WIN * 4];
    int t = threadIdx.x;
    for (int i = t; i < WIN * 4; i += 1024) acc[i] = 0.0f;
    __syncthreads();
    int bin = blockIdx.x;
    int cnt = bin_cnt[bin];
    const unsigned* bp = binned + (size_t)bin * CAP;
    constexpr int P = 4;
    for (int k0 = t; k0 < cnt; k0 += P * 1024) {
        unsigned w[P];
        uint2 q[P];
#pragma unroll
        for (int p = 0; p < P; p++) {
            int k = k0 + p * 1024;
            w[p] = (k < cnt) ? bp[k] : INVW;
        }
#pragma unroll
        for (int p = 0; p < P; p++) {
            unsigned s = min(w[p] & 0x3FFFFu, (unsigned)(N_NODES - 1));
            q[p] = *(const uint2*)&y3b[(size_t)s * 2u];
        }
#pragma unroll
        for (int p = 0; p < P; p++) {
            if (w[p] != INVW) {
                unsigned f = w[p] >> 18;
                float* a = &acc[f * 4u];
                atomicAdd(a + 0, blo(q[p].x)); atomicAdd(a + 1, bhi(q[p].x));
                atomicAdd(a + 2, blo(q[p].y)); atomicAdd(a + 3, bhi(q[p].y));
            }
        }
    }
    __syncthreads();
    int n0 = bin << BINB;
    int nodes = min(WIN, N_NODES - n0);
    for (int idx = t; idx < nodes * 4; idx += 1024)
        agg[(size_t)n0 * 4u + idx] = acc[idx];
}

// ---- Node-side fused linears -------------------------------------------

// h1 = lrelu(agg13/cnt @W1l + b1 + x@W1r); y2b = bf16(h1@W2l); z2 = h1@W2r
__global__ void fused1(const float* __restrict__ agg, const float* __restrict__ x,
                       const float* __restrict__ cntf,
                       const float* __restrict__ W1l, const float* __restrict__ b1,
                       const float* __restrict__ W1r, const float* __restrict__ W2l,
                       const float* __restrict__ W2r,
                       unsigned* __restrict__ y2b, float* __restrict__ z2) {
    __shared__ float sWl[208], sWr[208], sb[16], sA[128], sB[128];
    for (int i = threadIdx.x; i < 208; i += blockDim.x) { sWl[i] = W1l[i]; sWr[i] = W1r[i]; }
    for (int i = threadIdx.x; i < 128; i += blockDim.x) { sA[i] = W2l[i]; sB[i] = W2r[i]; }
    if (threadIdx.x < 16) sb[threadIdx.x] = b1[threadIdx.x];
    __syncthreads();
    int n = blockIdx.x * blockDim.x + threadIdx.x;
    if (n >= N_NODES) return;
    float inv = 1.0f / fmaxf(cntf[n], 1.0f);
    float a[13], xv[13];
#pragma unroll
    for (int i = 0; i < 13; i++) { a[i] = agg[n * 13 + i] * inv; xv[i] = x[n * 13 + i]; }
    float h[16];
#pragma unroll
    for (int o = 0; o < 16; o++) {
        float acc = sb[o];
#pragma unroll
        for (int i = 0; i < 13; i++) acc += a[i] * sWl[i * 16 + o] + xv[i] * sWr[i * 16 + o];
        h[o] = lrelu(acc);
    }
    float ya[8];
#pragma unroll
    for (int o2 = 0; o2 < 8; o2++) {
        float y = 0.0f, za = 0.0f;
#pragma unroll
        for (int o = 0; o < 16; o++) { y += h[o] * sA[o * 8 + o2]; za += h[o] * sB[o * 8 + o2]; }
        ya[o2] = y;
        z2[n * 8 + o2] = za;
    }
    uint4 out;
    out.x = pk(ya[0], ya[1]); out.y = pk(ya[2], ya[3]);
    out.z = pk(ya[4], ya[5]); out.w = pk(ya[6], ya[7]);
    *(uint4*)&y2b[(size_t)n * 4u] = out;
}

// h2 = lrelu(agg8/cnt + b2 + z2) (in place over z2); y3b = bf16(h2@W3l)
__global__ void fused2(const float* __restrict__ agg8, const float* __restrict__ cntf,
                       const float* __restrict__ b2, const float* __restrict__ W3l,
                       float* __restrict__ z2h2, unsigned* __restrict__ y3b) {
    __shared__ float sb[8], sW3[32];
    if (threadIdx.x < 8) sb[threadIdx.x] = b2[threadIdx.x];
    if (threadIdx.x < 32) sW3[threadIdx.x] = W3l[threadIdx.x];
    __syncthreads();
    int n = blockIdx.x * blockDim.x + threadIdx.x;
    if (n >= N_NODES) return;
    float inv = 1.0f / fmaxf(cntf[n], 1.0f);
    float h2v[8];
#pragma unroll
    for (int j = 0; j < 8; j++) {
        float v = agg8[n * 8 + j] * inv + sb[j] + z2h2[n * 8 + j];
        h2v[j] = lrelu(v);
        z2h2[n * 8 + j] = h2v[j];
    }
    float y[4];
#pragma unroll
    for (int k = 0; k < 4; k++) {
        float acc = 0.0f;
#pragma unroll
        for (int j = 0; j < 8; j++) acc += h2v[j] * sW3[j * 4 + k];
        y[k] = acc;
    }
    uint2 out;
    out.x = pk(y[0], y[1]); out.y = pk(y[2], y[3]);
    *(uint2*)&y3b[(size_t)n * 2u] = out;
}

// h3 = agg4/cnt + b3 + h2@W3r; pooled (sorted batch -> LDS window).
__global__ void pool_k(const float* __restrict__ agg4, const float* __restrict__ h2,
                       const float* __restrict__ cntf,
                       const float* __restrict__ W3r, const float* __restrict__ b3,
                       const int* __restrict__ batch,
                       float* __restrict__ pool, float* __restrict__ gcnt) {
    __shared__ float sW[32], sb[4];
    __shared__ float lp[16][4];
    __shared__ float lc[16];
    __shared__ int sbase;
    if (threadIdx.x < 32) sW[threadIdx.x] = W3r[threadIdx.x];
    if (threadIdx.x < 4) sb[threadIdx.x] = b3[threadIdx.x];
    if (threadIdx.x < 16) {
        lc[threadIdx.x] = 0.0f;
        for (int k = 0; k < 4; k++) lp[threadIdx.x][k] = 0.0f;
    }
    int n0 = blockIdx.x * blockDim.x;
    if (threadIdx.x == 0) sbase = batch[n0 < N_NODES ? n0 : N_NODES - 1];
    __syncthreads();
    int n = n0 + threadIdx.x;
    if (n < N_NODES) {
        int b = batch[n];
        float inv = 1.0f / fmaxf(cntf[n], 1.0f);
        float h2v[8];
#pragma unroll
        for (int j = 0; j < 8; j++) h2v[j] = h2[n * 8 + j];
        int off = b - sbase;
        bool local = (off >= 0 && off < 16);
#pragma unroll
        for (int k = 0; k < 4; k++) {
            float z = 0.0f;
#pragma unroll
            for (int j = 0; j < 8; j++) z += h2v[j] * sW[j * 4 + k];
            float v = agg4[n * 4 + k] * inv + sb[k] + z;
            if (local) atomicAdd(&lp[off][k], v);
            else atomicAdd(&pool[b * 4 + k], v);
        }
        if (local) atomicAdd(&lc[off], 1.0f);
        else atomicAdd(&gcnt[b], 1.0f);
    }
    __syncthreads();
    if (threadIdx.x < 16) {
        int b = sbase + threadIdx.x;
        float c = lc[threadIdx.x];
        if (c > 0.0f && b < N_GRAPHS) {
            atomicAdd(&gcnt[b], c);
            for (int k = 0; k < 4; k++) atomicAdd(&pool[b * 4 + k], lp[threadIdx.x][k]);
        }
    }
}

__global__ void final_k(const float* __restrict__ pool, const float* __restrict__ gcnt,
                        const float* __restrict__ Wc, const float* __restrict__ bc,
                        float* __restrict__ out) {
    int g = blockIdx.x * blockDim.x + threadIdx.x;
    if (g >= N_GRAPHS) return;
    float inv = 1.0f / fmaxf(gcnt[g], 1.0f);
    float acc = bc[0];
#pragma unroll
    for (int k = 0; k < 4; k++) {
        float ap = pool[g * 4 + k];
        acc += ap * inv * Wc[k] + ap * Wc[4 + k];
    }
    out[g] = acc;
}

extern "C" void kernel_launch(void* const* d_in, const int* in_sizes, int n_in,
                              void* d_out, int out_size, void* d_ws, size_t ws_size,
                              hipStream_t stream) {
    const float* x = (const float*)d_in[0];
    const int* ei = (const int*)d_in[1];
    const int* src = ei;
    const int* dst = ei + N_EDGES;
    const int* batch = (const int*)d_in[2];
    const float* W1l = (const float*)d_in[3];
    const float* b1 = (const float*)d_in[4];
    const float* W1r = (const float*)d_in[5];
    const float* W2l = (const float*)d_in[6];
    const float* b2 = (const float*)d_in[7];
    const float* W2r = (const float*)d_in[8];
    const float* W3l = (const float*)d_in[9];
    const float* b3 = (const float*)d_in[10];
    const float* W3r = (const float*)d_in[11];
    const float* Wc = (const float*)d_in[12];
    const float* bc = (const float*)d_in[13];
    float* out = (float*)d_out;

    const size_t N = N_NODES;
    // layout: binned (18 MB) | bin_cnt | agg 13N f | cntf N | z2 8N f |
    //         x16b 8N u32 | y2b 4N u32... wait sizes in u32 units below
    unsigned* binned = (unsigned*)d_ws;
    int* bin_cnt = (int*)(binned + (size_t)NBINS * CAP);
    float* fbase = (float*)(bin_cnt + 512);
    float* agg = fbase;                         // 13N floats (reused 8N / 4N)
    float* cntf = fbase + 13 * N;               // N
    float* z2 = cntf + N;                       // 8N (becomes h2 in place)
    unsigned* x16b = (unsigned*)(z2 + 8 * N);   // 8N u32 (16 bf16/row)
    unsigned* y2b = x16b + 8 * N;               // 4N u32 (8 bf16/row)
    unsigned* y3b = y2b + 4 * N;                // 2N u32 (4 bf16/row)
    float* pool = (float*)(y3b + 2 * N);        // 2048
    float* gcnt = pool + N_GRAPHS * 4;          // 512

    const int TPB = 256;
    const int NB = (N_NODES + TPB - 1) / TPB;

    hipMemsetAsync(bin_cnt, 0, 512 * sizeof(int), stream);
    hipMemsetAsync(pool, 0, N_GRAPHS * 5 * sizeof(float), stream);

    // Prep: bf16-pack x to 32-B rows; bin edges by dst>>9.
    pack_x<<<(N_NODES * 8 + TPB - 1) / TPB, TPB, 0, stream>>>(x, x16b);
    partition_k<<<PART_BLOCKS, TPB, 0, stream>>>(src, dst, bin_cnt, binned);

    // Layer 1: LDS-aggregate x16b (13 dims + degree), fused node linear.
    agg13_k<<<NBINS, 1024, 0, stream>>>(x16b, binned, bin_cnt, agg, cntf);
    fused1<<<NB, TPB, 0, stream>>>(agg, x, cntf, W1l, b1, W1r, W2l, W2r, y2b, z2);

    // Layer 2: LDS-aggregate y2b (8 dims), epilogue -> h2 (in z2), y3b.
    agg8_k<<<NBINS, 1024, 0, stream>>>(y2b, binned, bin_cnt, agg);
    fused2<<<NB, TPB, 0, stream>>>(agg, cntf, b2, W3l, z2, y3b);

    // Layer 3: LDS-aggregate y3b (4 dims), epilogue + pooling.
    agg4_k<<<NBINS, 1024, 0, stream>>>(y3b, binned, bin_cnt, agg);
    pool_k<<<NB, TPB, 0, stream>>>(agg, z2, cntf, W3r, b3, batch, pool, gcnt);

    final_k<<<2, TPB, 0, stream>>>(pool, gcnt, Wc, bc, out);
}